// Round 5
// baseline (237.096 us; speedup 1.0000x reference)
//
#include <hip/hip_runtime.h>
#include <hip/hip_bf16.h>

// SatelliteSpecificNormalization:
//   x: (B=16, N=8, C=1, H=512, W=512) f32, sids (B,N) in [-1,8),
//   weight/bias (8,) f32.  out = valid ? x*w[sid]+b[sid] : x
//
// R4 state: kernel < 78.8us (below the harness poison fills in top-5).
// Floor: ~201 MB HBM traffic at 6.7 TB/s (fill-measured ceiling) ~= 30-40us.
// This round: ILP-8 (128 B in flight/thread), exact grid (no bound checks),
// block-uniform slab (2048 | 65536) -> no LDS, no syncthreads; (w,b) are
// block-uniform broadcast loads. NT stores keep output from evicting
// L3-warm input.

typedef float floatx4 __attribute__((ext_vector_type(4)));

#define LOG2_VEC_PER_SLAB 16   // (C*H*W)/4 = 65536 float4 per slab
#define ILP 8
#define BLOCK 256
#define PER_BLOCK (BLOCK * ILP)   // 2048 float4s; divides 65536 -> slab uniform per block

__global__ __launch_bounds__(BLOCK) void sat_norm_fast(
    const floatx4* __restrict__ x,
    const int* __restrict__ sids,
    const float* __restrict__ weight,
    const float* __restrict__ bias,
    floatx4* __restrict__ out) {
    // slab is uniform across the whole block
    const int slab = (int)((blockIdx.x * (unsigned)PER_BLOCK) >> LOG2_VEC_PER_SLAB);
    const int sid  = sids[slab];
    const bool valid = sid >= 0;
    const float w = valid ? weight[sid] : 1.0f;
    const float b = valid ? bias[sid]   : 0.0f;

    const int base = blockIdx.x * PER_BLOCK + threadIdx.x;

    floatx4 xv[ILP];
#pragma unroll
    for (int k = 0; k < ILP; ++k) xv[k] = x[base + k * BLOCK];
#pragma unroll
    for (int k = 0; k < ILP; ++k) {
        floatx4 ov;
        ov.x = fmaf(xv[k].x, w, b);
        ov.y = fmaf(xv[k].y, w, b);
        ov.z = fmaf(xv[k].z, w, b);
        ov.w = fmaf(xv[k].w, w, b);
        __builtin_nontemporal_store(ov, &out[base + k * BLOCK]);
    }
}

// Generic fallback (tail-safe), only used if sizes ever change.
__global__ __launch_bounds__(BLOCK) void sat_norm_generic(
    const floatx4* __restrict__ x,
    const int* __restrict__ sids,
    const float* __restrict__ weight,
    const float* __restrict__ bias,
    floatx4* __restrict__ out,
    int n_vec) {
    const int stride = gridDim.x * blockDim.x;
    for (int v = blockIdx.x * blockDim.x + threadIdx.x; v < n_vec; v += stride) {
        const int slab = v >> LOG2_VEC_PER_SLAB;
        const int sid = sids[slab];
        const bool valid = sid >= 0;
        const float w = valid ? weight[sid] : 1.0f;
        const float b = valid ? bias[sid]   : 0.0f;
        const floatx4 xv = x[v];
        floatx4 ov;
        ov.x = fmaf(xv.x, w, b);
        ov.y = fmaf(xv.y, w, b);
        ov.z = fmaf(xv.z, w, b);
        ov.w = fmaf(xv.w, w, b);
        __builtin_nontemporal_store(ov, &out[v]);
    }
}

extern "C" void kernel_launch(void* const* d_in, const int* in_sizes, int n_in,
                              void* d_out, int out_size, void* d_ws, size_t ws_size,
                              hipStream_t stream) {
    const floatx4* x     = (const floatx4*)d_in[0];
    const int*    sids   = (const int*)d_in[1];
    const float*  weight = (const float*)d_in[2];
    const float*  bias   = (const float*)d_in[3];
    floatx4* out = (floatx4*)d_out;

    const int n_vec = out_size / 4;                  // 8,388,608 = 2^23
    if ((n_vec % PER_BLOCK) == 0) {
        const int blocks = n_vec / PER_BLOCK;        // 4096, exact
        sat_norm_fast<<<blocks, BLOCK, 0, stream>>>(x, sids, weight, bias, out);
    } else {
        int blocks = (n_vec + BLOCK - 1) / BLOCK;
        if (blocks > 2048) blocks = 2048;
        sat_norm_generic<<<blocks, BLOCK, 0, stream>>>(x, sids, weight, bias, out, n_vec);
    }
}